// Round 6
// baseline (229.928 us; speedup 1.0000x reference)
//
#include <hip/hip_runtime.h>

#define D_DIM 128
#define N_DIM 8192
#define B_DIM 32
#define KSPL 32
#define KC   256     // N_DIM / KSPL rows per block
#define BK   128     // k-rows per LDS fill (36 KB LDS -> 4 blocks/CU)

typedef float f32x4 __attribute__((ext_vector_type(4)));
typedef short bf16x8 __attribute__((ext_vector_type(8)));
typedef unsigned short u16;

__device__ __forceinline__ u16 f2bf(float f) {
    unsigned int u = __builtin_bit_cast(unsigned int, f);
    u += 0x7FFFu + ((u >> 16) & 1u);   // round-to-nearest-even
    return (u16)(u >> 16);
}

// Load one 64-row chunk: thread (dc,nr) takes rows gc*64 + sub*32 + 4*nr + i,
// cols 4*dc..4*dc+3.
__device__ __forceinline__ void load_chunk(f32x4 (&buf)[8], const float* src,
                                           int gc, int nr, int dc) {
    const float* p = src + (size_t)gc * 64 * D_DIM;
#pragma unroll
    for (int sub = 0; sub < 2; ++sub)
#pragma unroll
        for (int i = 0; i < 4; ++i)
            buf[sub * 4 + i] =
                *(const f32x4*)(p + (size_t)(sub * 32 + 4 * nr + i) * D_DIM + 4 * dc);
}

// Column sums + fp32->bf16 + swizzled LDS write (no barrier; waves write
// disjoint k-rows). LDS layout (BK=128): (d,k) at
// d*128 + (((k>>3) ^ (d&7))*8) + (k&7), k = local 0..127.
__device__ __forceinline__ void proc_write(u16* lds, f32x4 (&buf)[8],
                                           float (&sum4)[4], int gc, int nr, int dc) {
#pragma unroll
    for (int x = 0; x < 8; ++x)
#pragma unroll
        for (int j = 0; j < 4; ++j) sum4[j] += buf[x][j];
#pragma unroll
    for (int sub = 0; sub < 2; ++sub)
#pragma unroll
        for (int j = 0; j < 4; ++j) {
            ushort4 w;
            w.x = f2bf(buf[sub * 4 + 0][j]);
            w.y = f2bf(buf[sub * 4 + 1][j]);
            w.z = f2bf(buf[sub * 4 + 2][j]);
            w.w = f2bf(buf[sub * 4 + 3][j]);
            int d = 4 * dc + j;
            int g = (gc & 1) * 8 + sub * 4 + (nr >> 1);  // 16B granule of local k
            int slot = g ^ (d & 7);
            *(ushort4*)(lds + d * 128 + slot * 8 + 4 * (nr & 1)) = w;
        }
}

// MFMA over the 128-k LDS buffer. Runtime wv only ever in ADDRESSES (dynamic
// local-array indexing demotes to scratch — round-1 lesson).
__device__ __forceinline__ void mfma_phase(const u16* lds, f32x4 (&acc)[2][8],
                                           int wv, int m, int q) {
#pragma unroll
    for (int h = 0; h < 4; ++h) {
        int slotbase = h * 4 + q;
        bf16x8 Fcol[8];
#pragma unroll
        for (int tt = 0; tt < 8; ++tt) {
            int slot = slotbase ^ (m & 7);
            Fcol[tt] = *(const bf16x8*)(lds + (16 * tt + m) * 128 + slot * 8);
        }
        bf16x8 Frow0, Frow1;
        {
            int slot = slotbase ^ (m & 7);
            Frow0 = *(const bf16x8*)(lds + (32 * wv + m) * 128 + slot * 8);
            Frow1 = *(const bf16x8*)(lds + (32 * wv + 16 + m) * 128 + slot * 8);
        }
#pragma unroll
        for (int c = 0; c < 8; ++c)
            acc[0][c] = __builtin_amdgcn_mfma_f32_16x16x32_bf16(Frow0, Fcol[c],
                                                                acc[0][c], 0, 0, 0);
#pragma unroll
        for (int c = 0; c < 8; ++c)
            acc[1][c] = __builtin_amdgcn_mfma_f32_16x16x32_bf16(Frow1, Fcol[c],
                                                                acc[1][c], 0, 0, 0);
    }
}

// NO min-waves arg in __launch_bounds__: rounds 1-5 show achieved waves/CU
// pinned at ~4x the 2nd arg (R4: 21.8% occ with grid/VGPR/LDS all allowing
// more) — on this toolchain it acts as a cap, not a minimum. (256,4) also
// forced VGPR 64 + 142 MB spill (R3). Occupancy now comes from grid
// (KSPL=32 -> 4 blocks/CU) and LDS (36 KB -> 4 blocks/CU).
__global__ __launch_bounds__(256) void cov_partial(
    const float* __restrict__ in, float* __restrict__ ws_p,
    float* __restrict__ ws_s) {
    __shared__ u16 lds[D_DIM * BK];     // 32 KB
    __shared__ float red[8][D_DIM];     // 4 KB

    const int t    = threadIdx.x;
    const int b    = blockIdx.y;
    const int ks   = blockIdx.x;
    const int dc   = t >> 3;
    const int nr   = t & 7;
    const int wv   = t >> 6;
    const int lane = t & 63;
    const int m    = lane & 15;
    const int q    = lane >> 4;

    const float* src = in + (size_t)b * (N_DIM * D_DIM) + (size_t)ks * KC * D_DIM;

    f32x4 acc[2][8];
#pragma unroll
    for (int r = 0; r < 2; ++r)
#pragma unroll
        for (int c = 0; c < 8; ++c) acc[r][c] = (f32x4)0.0f;
    float sum4[4] = {0.f, 0.f, 0.f, 0.f};

    f32x4 bufA[8], bufB[8];

    // ---- phase 0: k = 0..127 (chunks 0,1) ----
    load_chunk(bufA, src, 0, nr, dc);
    load_chunk(bufB, src, 1, nr, dc);
    proc_write(lds, bufA, sum4, 0, nr, dc);
    proc_write(lds, bufB, sum4, 1, nr, dc);
    __syncthreads();
    mfma_phase(lds, acc, wv, m, q);
    __syncthreads();

    // ---- phase 1: k = 128..255 (chunks 2,3) ----
    load_chunk(bufA, src, 2, nr, dc);
    load_chunk(bufB, src, 3, nr, dc);
    proc_write(lds, bufA, sum4, 2, nr, dc);
    proc_write(lds, bufB, sum4, 3, nr, dc);
    __syncthreads();
    mfma_phase(lds, acc, wv, m, q);

    // ---- column-sum reduction across the 8 n-octets ----
    __syncthreads();
#pragma unroll
    for (int j = 0; j < 4; ++j) red[nr][4 * dc + j] = sum4[j];
    __syncthreads();
    if (t < D_DIM) {
        float ssum = 0.f;
#pragma unroll
        for (int i = 0; i < 8; ++i) ssum += red[i][t];
        ws_s[(size_t)(b * KSPL + ks) * D_DIM + t] = ssum;
    }

    // ---- dump partial product in RAW fragment order (coalesced float4) ----
    f32x4* outv = (f32x4*)(ws_p + (size_t)(b * KSPL + ks) * (D_DIM * D_DIM));
#pragma unroll
    for (int r = 0; r < 2; ++r)
#pragma unroll
        for (int c = 0; c < 8; ++c)
            outv[t * 16 + r * 8 + c] = acc[r][c];
}

// Kernel 2: sum partials (float4), decode fragment layout, subtract mean
// outer product, write cov.
__global__ __launch_bounds__(256) void cov_reduce(
    const float* __restrict__ ws_p, const float* __restrict__ ws_s,
    float* __restrict__ out, int kspl) {
    int b = blockIdx.x >> 4;
    int chunk = blockIdx.x & 15;
    int g = chunk * 256 + threadIdx.x;   // float4 index, 0..4095

    __shared__ float mean[D_DIM];
    if (threadIdx.x < D_DIM) {
        float s = 0.f;
        for (int ks = 0; ks < kspl; ++ks)
            s += ws_s[(size_t)(b * kspl + ks) * D_DIM + threadIdx.x];
        mean[threadIdx.x] = s * (1.0f / (float)N_DIM);
    }
    __syncthreads();

    const f32x4* pv = (const f32x4*)ws_p;
    f32x4 acc = (f32x4)0.0f;
    for (int ks = 0; ks < kspl; ++ks) {
        f32x4 v = pv[(size_t)(b * kspl + ks) * (D_DIM * D_DIM / 4) + g];
        acc.x += v.x; acc.y += v.y; acc.z += v.z; acc.w += v.w;
    }

    // decode: flat float index f = 4*g + i = t2*64 + (r*8+c)*4 + i
    int t2 = g >> 4;
    int rc = g & 15;
    int r = rc >> 3, c = rc & 7;
    int wv = t2 >> 6;
    int lane = t2 & 63;
    int m = lane & 15;
    int q = lane >> 4;
    int d0 = 32 * wv + 16 * r + 4 * q;
    int e = 16 * c + m;

    const float invN = 1.0f / (float)N_DIM;
    float me = mean[e];
    float* ob = out + (size_t)b * (D_DIM * D_DIM);
#pragma unroll
    for (int i = 0; i < 4; ++i) {
        int d = d0 + i;
        ob[(size_t)d * D_DIM + e] = acc[i] * invN - mean[d] * me;
    }
}

extern "C" void kernel_launch(void* const* d_in, const int* in_sizes, int n_in,
                              void* d_out, int out_size, void* d_ws, size_t ws_size,
                              hipStream_t stream) {
    const float* in = (const float*)d_in[0];
    float* out = (float*)d_out;

    float* ws_p = (float*)d_ws;
    float* ws_s = ws_p + (size_t)KSPL * B_DIM * (D_DIM * D_DIM);

    cov_partial<<<dim3(KSPL, B_DIM), 256, 0, stream>>>(in, ws_p, ws_s);
    cov_reduce<<<dim3(B_DIM * 16), 256, 0, stream>>>(ws_p, ws_s, out, KSPL);
}

// Round 7
// 226.180 us; speedup vs baseline: 1.0166x; 1.0166x over previous
//
#include <hip/hip_runtime.h>

#define D_DIM 128
#define N_DIM 8192
#define B_DIM 32
#define KSPL 32
#define KC   256     // N_DIM / KSPL rows per block

typedef float f32x4 __attribute__((ext_vector_type(4)));
typedef short bf16x8 __attribute__((ext_vector_type(8)));
typedef unsigned short u16;

using gvp = const __attribute__((address_space(1))) void*;
using lvp = __attribute__((address_space(3))) void*;

__device__ __forceinline__ u16 f2bf(float f) {
    unsigned int u = __builtin_bit_cast(unsigned int, f);
    u += 0x7FFFu + ((u >> 16) & 1u);   // round-to-nearest-even
    return (u16)(u >> 16);
}

// Async-stage one 32-row chunk (32 rows x 128 f32) into stage[] via
// global_load_lds width=16 (fire-and-forget DMA, vmcnt-tracked).
// LDS dest is wave-uniform base + lane*16 (HW constraint), so the
// bank-conflict swizzle lives in the per-lane GLOBAL address:
// stage row kl, 16B-slot s holds global granule (s ^ (kl & 31)).
__device__ __forceinline__ void stage_issue(const float* gsrc_chunk, float* stage,
                                            int wv, int lane) {
    const int half = lane >> 5;     // which row of the instruction's 2-row span
    const int sl   = lane & 31;     // slot this lane fills
#pragma unroll
    for (int i = 0; i < 4; ++i) {
        int kl = 8 * wv + 2 * i + half;          // row within chunk
        int gg = sl ^ (kl & 31);                 // swizzled global granule
        const float* gp = gsrc_chunk + (size_t)kl * D_DIM + gg * 4;
        float* lp = stage + (8 * wv + 2 * i) * D_DIM;   // wave-uniform base
        __builtin_amdgcn_global_load_lds((gvp)gp, (lvp)lp, 16, 0, 0);
    }
}

// Pass 2: read staged fp32 (b128, 2-way conflict-free via the stage swizzle),
// accumulate column sums, convert once per element, write the bf16
// transposed tile [d=128][k=64]: (d,k) at d*64 + ((k>>3)^(d&7))*8 + (k&7).
__device__ __forceinline__ void pass2_chunk(const float* stage, u16* tile,
                                            float (&sum4)[4], int c /*0 or 1*/,
                                            int nr, int dc) {
    f32x4 v[4];
#pragma unroll
    for (int i = 0; i < 4; ++i) {
        int kl = 4 * nr + i;
        int slot = (dc ^ kl) & 31;               // slot holding true granule dc
        v[i] = *(const f32x4*)(stage + (size_t)kl * D_DIM + slot * 4);
    }
#pragma unroll
    for (int i = 0; i < 4; ++i)
#pragma unroll
        for (int j = 0; j < 4; ++j) sum4[j] += v[i][j];
#pragma unroll
    for (int j = 0; j < 4; ++j) {
        ushort4 w;
        w.x = f2bf(v[0][j]); w.y = f2bf(v[1][j]);
        w.z = f2bf(v[2][j]); w.w = f2bf(v[3][j]);
        int d = 4 * dc + j;
        int g = c * 4 + (nr >> 1);               // 16B granule of tile-local k
        int slot = g ^ (d & 7);
        *(ushort4*)(tile + d * 64 + slot * 8 + 4 * (nr & 1)) = w;
    }
}

// MFMA over the 64-k bf16 tile (R2-proven layout). Runtime wv only ever in
// ADDRESSES (dynamic local-array indexing demotes to scratch — R1 lesson).
__device__ __forceinline__ void mfma_phase64(const u16* tile, f32x4 (&acc)[2][8],
                                             int wv, int m, int q) {
#pragma unroll
    for (int h = 0; h < 2; ++h) {
        int slot = (4 * h + q) ^ (m & 7);
        bf16x8 Fcol[8];
#pragma unroll
        for (int tt = 0; tt < 8; ++tt)
            Fcol[tt] = *(const bf16x8*)(tile + (16 * tt + m) * 64 + slot * 8);
        bf16x8 Frow0 = *(const bf16x8*)(tile + (32 * wv + m) * 64 + slot * 8);
        bf16x8 Frow1 = *(const bf16x8*)(tile + (32 * wv + 16 + m) * 64 + slot * 8);
#pragma unroll
        for (int c = 0; c < 8; ++c)
            acc[0][c] = __builtin_amdgcn_mfma_f32_16x16x32_bf16(Frow0, Fcol[c],
                                                                acc[0][c], 0, 0, 0);
#pragma unroll
        for (int c = 0; c < 8; ++c)
            acc[1][c] = __builtin_amdgcn_mfma_f32_16x16x32_bf16(Frow1, Fcol[c],
                                                                acc[1][c], 0, 0, 0);
    }
}

// LDS: 2x16 KB fp32 stage + 16 KB bf16 tile + 4 KB red = 52 KB -> 3 blocks/CU.
// No min-waves arg: (256,4) spilled (R3); cap theory dead (R6) but VGPR~160
// with 3 blocks/CU is consistent.
__global__ __launch_bounds__(256) void cov_partial(
    const float* __restrict__ in, float* __restrict__ ws_p,
    float* __restrict__ ws_s) {
    __shared__ float stg0[32 * D_DIM];   // 16 KB
    __shared__ float stg1[32 * D_DIM];   // 16 KB
    __shared__ u16 tile[D_DIM * 64];     // 16 KB
    __shared__ float red[8][D_DIM];      // 4 KB

    const int t    = threadIdx.x;
    const int b    = blockIdx.y;
    const int ks   = blockIdx.x;
    const int dc   = t >> 3;
    const int nr   = t & 7;
    const int wv   = t >> 6;
    const int lane = t & 63;
    const int m    = lane & 15;
    const int q    = lane >> 4;

    const float* src = in + (size_t)b * (N_DIM * D_DIM) + (size_t)ks * KC * D_DIM;

    f32x4 acc[2][8];
#pragma unroll
    for (int r = 0; r < 2; ++r)
#pragma unroll
        for (int c = 0; c < 8; ++c) acc[r][c] = (f32x4)0.0f;
    float sum4[4] = {0.f, 0.f, 0.f, 0.f};

    // prologue: DMA chunks 0,1 into the two stage buffers
    stage_issue(src, stg0, wv, lane);
    stage_issue(src + 32 * D_DIM, stg1, wv, lane);
    __syncthreads();   // vmcnt(0) drain: staged data visible

    for (int p = 0; p < 4; ++p) {
        // convert staged fp32 -> bf16 tile (k = 0..63 of this phase) + sums
        pass2_chunk(stg0, tile, sum4, 0, nr, dc);
        pass2_chunk(stg1, tile, sum4, 1, nr, dc);
        __syncthreads();   // tile ready; stage buffers free

        // issue next phase's DMAs BEFORE mfma — loads fly during compute
        if (p < 3) {
            stage_issue(src + (size_t)(2 * p + 2) * 32 * D_DIM, stg0, wv, lane);
            stage_issue(src + (size_t)(2 * p + 3) * 32 * D_DIM, stg1, wv, lane);
        }
        mfma_phase64(tile, acc, wv, m, q);
        __syncthreads();   // tile reads done; next pass2 may overwrite; DMAs landed
    }

    // column-sum reduction across the 8 n-octets
#pragma unroll
    for (int j = 0; j < 4; ++j) red[nr][4 * dc + j] = sum4[j];
    __syncthreads();
    if (t < D_DIM) {
        float ssum = 0.f;
#pragma unroll
        for (int i = 0; i < 8; ++i) ssum += red[i][t];
        ws_s[(size_t)(b * KSPL + ks) * D_DIM + t] = ssum;
    }

    // dump partial product in RAW fragment order (coalesced float4)
    f32x4* outv = (f32x4*)(ws_p + (size_t)(b * KSPL + ks) * (D_DIM * D_DIM));
#pragma unroll
    for (int r = 0; r < 2; ++r)
#pragma unroll
        for (int c = 0; c < 8; ++c)
            outv[t * 16 + r * 8 + c] = acc[r][c];
}

// Kernel 2: sum partials (float4), decode fragment layout, subtract mean
// outer product, write cov.
__global__ __launch_bounds__(256) void cov_reduce(
    const float* __restrict__ ws_p, const float* __restrict__ ws_s,
    float* __restrict__ out, int kspl) {
    int b = blockIdx.x >> 4;
    int chunk = blockIdx.x & 15;
    int g = chunk * 256 + threadIdx.x;   // float4 index, 0..4095

    __shared__ float mean[D_DIM];
    if (threadIdx.x < D_DIM) {
        float s = 0.f;
        for (int ks = 0; ks < kspl; ++ks)
            s += ws_s[(size_t)(b * kspl + ks) * D_DIM + threadIdx.x];
        mean[threadIdx.x] = s * (1.0f / (float)N_DIM);
    }
    __syncthreads();

    const f32x4* pv = (const f32x4*)ws_p;
    f32x4 acc = (f32x4)0.0f;
    for (int ks = 0; ks < kspl; ++ks) {
        f32x4 v = pv[(size_t)(b * kspl + ks) * (D_DIM * D_DIM / 4) + g];
        acc.x += v.x; acc.y += v.y; acc.z += v.z; acc.w += v.w;
    }

    // decode: flat float index f = 4*g + i = t2*64 + (r*8+c)*4 + i
    int t2 = g >> 4;
    int rc = g & 15;
    int r = rc >> 3, c = rc & 7;
    int wv = t2 >> 6;
    int lane = t2 & 63;
    int m = lane & 15;
    int q = lane >> 4;
    int d0 = 32 * wv + 16 * r + 4 * q;
    int e = 16 * c + m;

    const float invN = 1.0f / (float)N_DIM;
    float me = mean[e];
    float* ob = out + (size_t)b * (D_DIM * D_DIM);
#pragma unroll
    for (int i = 0; i < 4; ++i) {
        int d = d0 + i;
        ob[(size_t)d * D_DIM + e] = acc[i] * invN - mean[d] * me;
    }
}

extern "C" void kernel_launch(void* const* d_in, const int* in_sizes, int n_in,
                              void* d_out, int out_size, void* d_ws, size_t ws_size,
                              hipStream_t stream) {
    const float* in = (const float*)d_in[0];
    float* out = (float*)d_out;

    float* ws_p = (float*)d_ws;
    float* ws_s = ws_p + (size_t)KSPL * B_DIM * (D_DIM * D_DIM);

    cov_partial<<<dim3(KSPL, B_DIM), 256, 0, stream>>>(in, ws_p, ws_s);
    cov_reduce<<<dim3(B_DIM * 16), 256, 0, stream>>>(ws_p, ws_s, out, KSPL);
}